// Round 6
// baseline (107.181 us; speedup 1.0000x reference)
//
#include <hip/hip_runtime.h>

#define HH 256
#define LL 4096
#define STR 72          // LDS row stride in shorts

// ws byte offsets (~6.2 MB used, rewritten every call)
#define WS_H  0
#define WS_P  (2u*1024*1024)
#define WS_R  (4u*1024*1024)
#define WS_C1 (6u*1024*1024)
#define WS_C2 (6u*1024*1024 + 128u*1024)

typedef __attribute__((ext_vector_type(8))) short short8;   // 8 bf16 = MFMA A/B frag
typedef __attribute__((ext_vector_type(4))) float f32x4;    // MFMA C/D frag

static __device__ inline unsigned short f2bf(float x) {
    union { float f; unsigned u; } v; v.f = x;
    unsigned r = v.u + 0x7fffu + ((v.u >> 16) & 1u);   // RNE
    return (unsigned short)(r >> 16);
}
static __device__ inline float bf2f(unsigned short us) {
    union { unsigned u; float f; } v; v.u = ((unsigned)us) << 16; return v.f;
}

#define CMUL(or_, oi_, ar_, ai_, br_, bi_) do { \
    float _tr = fmaf((ar_), (br_), -(ai_) * (bi_)); \
    float _ti = fmaf((ar_), (bi_), (ai_) * (br_)); \
    (or_) = _tr; (oi_) = _ti; } while (0)

// ---------------- Precompute: one block per h ----------------
// h[0] += D: folds the D*u term into the Toeplitz conv (delta filter tap),
// so the main kernel never needs u after mm1.
__global__ __launch_bounds__(256) void s4_pre_kernel(
    const float* __restrict__ theta, const float* __restrict__ a,
    const float* __restrict__ b_p,   const float* __restrict__ c_p,
    const float* __restrict__ x0,    const float* __restrict__ Dp,
    unsigned short* __restrict__ Hm, unsigned short* __restrict__ Pm,
    unsigned short* __restrict__ Rm, float4* __restrict__ C1,
    float* __restrict__ C2)
{
    const int tid = threadIdx.x;
    const int h   = blockIdx.x;
    const int d   = tid & 31;
    const int kb  = tid >> 5;
    const float T = 1.0f / (LL - 1);
    __shared__ float h_s[64];

    const float lr = a[h * 32 + d];
    const float li = theta[h * 32 + d];
    const float Dh = Dp[h];
    float sn, cS;
    sincosf(li * T, &sn, &cS);
    const float er = expf(lr * T);
    const float Rr = er * cS, Ri = er * sn;      // r = exp(ls*T)
    const float den = lr * lr + li * li;
    const float t0r = ((Rr - 1.f) * lr + Ri * li) / den;
    const float t0i = (Ri * lr - (Rr - 1.f) * li) / den;
    const float qq  = b_p[h * 32 + d] * c_p[h * 32 + d];
    const float wre = 2.f * qq * t0r, wim = 2.f * qq * t0i;
    const float vv  = 4.f * T * c_p[h * 32 + d] * x0[h * 32 + d];

    float r2r, r2i, r4r, r4i, r8r, r8i, r16r, r16i, r32r, r32i;
    CMUL(r2r, r2i, Rr, Ri, Rr, Ri);
    CMUL(r4r, r4i, r2r, r2i, r2r, r2i);
    CMUL(r8r, r8i, r4r, r4i, r4r, r4i);
    CMUL(r16r, r16i, r8r, r8i, r8r, r8i);
    CMUL(r32r, r32i, r16r, r16i, r16r, r16i);

    unsigned short* HmB = Hm + h * 4096;
    unsigned short* PmB = Pm + h * 4096;
    unsigned short* RmB = Rm + h * 4096;

    {   // fill Rmat, Pmat, reduce h_k
        float pr = 1.f, pi = 0.f;
        if (kb & 1) CMUL(pr, pi, pr, pi, r8r, r8i);
        if (kb & 2) CMUL(pr, pi, pr, pi, r16r, r16i);
        if (kb & 4) CMUL(pr, pi, pr, pi, r32r, r32i);
        #pragma unroll
        for (int k8 = 0; k8 < 8; ++k8) {
            const int k = (kb << 3) + k8;
            RmB[k * 64 + d]           = f2bf(pr);
            RmB[k * 64 + 32 + d]      = f2bf(-pi);
            PmB[d * 64 + (63 - k)]        = f2bf(pr);
            PmB[(32 + d) * 64 + (63 - k)] = f2bf(pi);
            float hk = fmaf(wre, pr, -wim * pi);     // Re(w * r^k)
            hk += __shfl_xor(hk, 1);
            hk += __shfl_xor(hk, 2);
            hk += __shfl_xor(hk, 4);
            hk += __shfl_xor(hk, 8);
            hk += __shfl_xor(hk, 16);
            if (d == 0) h_s[k] = hk + ((k == 0) ? Dh : 0.f);   // D fold
            CMUL(pr, pi, pr, pi, Rr, Ri);
        }
    }
    if (tid < 32) {
        float Ar, Ai, wrr, wri;
        CMUL(Ar, Ai, r32r, r32i, r32r, r32i);        // A = r^64
        CMUL(wrr, wri, wre, wim, Rr, Ri);            // w*r
        C1[h * 32 + d] = make_float4(Ar, Ai, wrr, wri);
        C2[h * 32 + d] = vv;
    }
    __syncthreads();

    {   // Toeplitz Hmat[t][tau] = h[t-tau]
        const int t  = tid >> 2;
        const int tb = (tid & 3) << 4;
        #pragma unroll
        for (int g = 0; g < 4; ++g) {
            const int tau0 = tb + (g << 2);
            unsigned short e[4];
            #pragma unroll
            for (int i = 0; i < 4; ++i) {
                const int dt = t - (tau0 + i);
                e[i] = (dt >= 0) ? f2bf(h_s[dt]) : (unsigned short)0;
            }
            uint2 pk;
            pk.x = (unsigned)e[0] | ((unsigned)e[1] << 16);
            pk.y = (unsigned)e[2] | ((unsigned)e[3] << 16);
            *(uint2*)&HmB[t * 64 + tau0] = pk;
        }
    }
}

// ---------------- Main: one block per (h, b-pair); 2 tiles MERGED ----------
// 5 barriers total; every phase carries both tiles (2x ILP per phase).
__global__ __launch_bounds__(256, 4) void s4_main_kernel(
    const float* __restrict__ u,
    const unsigned short* __restrict__ Hm, const unsigned short* __restrict__ Pm,
    const unsigned short* __restrict__ Rm, const float4* __restrict__ C1,
    const float* __restrict__ C2, float* __restrict__ out)
{
    const int tid = threadIdx.x;
    const int blk = blockIdx.x;           // 1024
    const int hh  = blk >> 2;
    const int bp  = blk & 3;              // b = 2bp, 2bp+1

    // LDS: 23 KB. UsX holds u bf16 [c][tau]; after mm1/mm2 it is reused as
    // EQ (E then Q, planar [c][dd]) for the same tile.
    __shared__ __align__(16) short UsA[64 * STR];
    __shared__ __align__(16) short UsB[64 * STR];
    __shared__ __align__(16) float Seg[2][32 * 18];

    const int d    = tid & 31;
    const int g    = tid >> 5;
    const int ln   = tid & 63;
    const int m0   = (tid >> 6) << 4;
    const int rowi = ln & 15;
    const int quad = ln >> 4;

    // ---- A-frags for all 3 matmuls -> registers ----
    const unsigned short* HmB = Hm + hh * 4096;
    const unsigned short* PmB = Pm + hh * 4096;
    const unsigned short* RmB = Rm + hh * 4096;
    short8 aH[2], aP[2], aR[2];
    #pragma unroll
    for (int kh = 0; kh < 2; ++kh) {
        const int off = (m0 + rowi) * 64 + (kh << 5) + (quad << 3);
        aH[kh] = *(const short8*)&HmB[off];
        aP[kh] = *(const short8*)&PmB[off];
        aR[kh] = *(const short8*)&RmB[off];
    }

    // ---- P0: stage both tiles ----
    const float* up0 = u + ((((size_t)(bp * 2) * HH) + hh) << 12);
    const float* up1 = u + ((((size_t)(bp * 2 + 1) * HH) + hh) << 12);
    float4 v0[4], v1[4];
    #pragma unroll
    for (int jj = 0; jj < 4; ++jj) v0[jj] = ((const float4*)up0)[tid + (jj << 8)];
    #pragma unroll
    for (int jj = 0; jj < 4; ++jj) v1[jj] = ((const float4*)up1)[tid + (jj << 8)];
    #pragma unroll
    for (int jj = 0; jj < 4; ++jj) {
        const int v  = tid + (jj << 8);
        const int c  = v >> 4;
        const int t0 = (v & 15) << 2;
        uint2 pk;
        pk.x = (unsigned)f2bf(v0[jj].x) | ((unsigned)f2bf(v0[jj].y) << 16);
        pk.y = (unsigned)f2bf(v0[jj].z) | ((unsigned)f2bf(v0[jj].w) << 16);
        *(uint2*)&UsA[c * STR + t0] = pk;
        pk.x = (unsigned)f2bf(v1[jj].x) | ((unsigned)f2bf(v1[jj].y) << 16);
        pk.y = (unsigned)f2bf(v1[jj].z) | ((unsigned)f2bf(v1[jj].w) << 16);
        *(uint2*)&UsB[c * STR + t0] = pk;
    }

    // ---- constants ----
    const float4 c1 = C1[hh * 32 + d];    // Ar, Ai, wr_r, wr_i
    const float vv  = C2[hh * 32 + d];
    const float Ar = c1.x, Ai = c1.y;
    float S8r, S8i, S16r, S16i, S32r, S32i;       // A^8, A^16, A^32
    {
        float b1r, b1i, b2r, b2i;
        CMUL(b1r, b1i, Ar, Ai, Ar, Ai);
        CMUL(b2r, b2i, b1r, b1i, b1r, b1i);
        CMUL(S8r, S8i, b2r, b2i, b2r, b2i);
        CMUL(S16r, S16i, S8r, S8i, S8r, S8i);
        CMUL(S32r, S32i, S16r, S16i, S16r, S16i);
    }
    __syncthreads();                               // B0: U ready

    // ---- P1: mm1+mm2 for BOTH tiles (32 MFMA), E kept in regs ----
    f32x4 accY0[4], accE0[4], accY1[4], accE1[4];
    #pragma unroll
    for (int nt = 0; nt < 4; ++nt) {
        accY0[nt] = (f32x4){0.f, 0.f, 0.f, 0.f};
        accE0[nt] = (f32x4){0.f, 0.f, 0.f, 0.f};
        accY1[nt] = (f32x4){0.f, 0.f, 0.f, 0.f};
        accE1[nt] = (f32x4){0.f, 0.f, 0.f, 0.f};
    }
    #pragma unroll
    for (int kh = 0; kh < 2; ++kh) {
        const int k0 = kh << 5;
        #pragma unroll
        for (int nt = 0; nt < 4; ++nt) {
            const int boff = ((nt << 4) + rowi) * STR + k0 + (quad << 3);
            const short8 bU0 = *(const short8*)&UsA[boff];
            const short8 bU1 = *(const short8*)&UsB[boff];
            accY0[nt] = __builtin_amdgcn_mfma_f32_16x16x32_bf16(aH[kh], bU0, accY0[nt], 0, 0, 0);
            accE0[nt] = __builtin_amdgcn_mfma_f32_16x16x32_bf16(aP[kh], bU0, accE0[nt], 0, 0, 0);
            accY1[nt] = __builtin_amdgcn_mfma_f32_16x16x32_bf16(aH[kh], bU1, accY1[nt], 0, 0, 0);
            accE1[nt] = __builtin_amdgcn_mfma_f32_16x16x32_bf16(aP[kh], bU1, accE1[nt], 0, 0, 0);
        }
    }
    __syncthreads();                               // B1: U reads done, regions free

    // ---- P2: write E planar over Us regions ----
    #pragma unroll
    for (int nt = 0; nt < 4; ++nt) {
        const int eoff = ((nt << 4) + rowi) * STR + m0 + (quad << 2);
        uint2 pk;
        pk.x = (unsigned)f2bf(accE0[nt][0]) | ((unsigned)f2bf(accE0[nt][1]) << 16);
        pk.y = (unsigned)f2bf(accE0[nt][2]) | ((unsigned)f2bf(accE0[nt][3]) << 16);
        *(uint2*)&UsA[eoff] = pk;
        pk.x = (unsigned)f2bf(accE1[nt][0]) | ((unsigned)f2bf(accE1[nt][1]) << 16);
        pk.y = (unsigned)f2bf(accE1[nt][2]) | ((unsigned)f2bf(accE1[nt][3]) << 16);
        *(uint2*)&UsB[eoff] = pk;
    }
    __syncthreads();                               // B2: E ready

    // ---- P3: scan phase a, both tiles (independent chains) ----
    const int cb = g << 3;
    float Er[2][8], Ei[2][8];
    {
        float Sr0 = 0.f, Si0 = 0.f, Sr1 = 0.f, Si1 = 0.f;
        #pragma unroll
        for (int i = 0; i < 8; ++i) {
            const int c = cb + i;
            Er[0][i] = bf2f((unsigned short)UsA[c * STR + d]);
            Ei[0][i] = bf2f((unsigned short)UsA[c * STR + 32 + d]);
            Er[1][i] = bf2f((unsigned short)UsB[c * STR + d]);
            Ei[1][i] = bf2f((unsigned short)UsB[c * STR + 32 + d]);
            float nr = fmaf(Ar, Sr0, fmaf(-Ai, Si0, Er[0][i]));
            float ni = fmaf(Ar, Si0, fmaf(Ai, Sr0, Ei[0][i]));
            Sr0 = nr; Si0 = ni;
            nr = fmaf(Ar, Sr1, fmaf(-Ai, Si1, Er[1][i]));
            ni = fmaf(Ar, Si1, fmaf(Ai, Sr1, Ei[1][i]));
            Sr1 = nr; Si1 = ni;
        }
        Seg[0][d * 18 + (g << 1)]     = Sr0;
        Seg[0][d * 18 + (g << 1) + 1] = Si0;
        Seg[1][d * 18 + (g << 1)]     = Sr1;
        Seg[1][d * 18 + (g << 1) + 1] = Si1;
    }
    __syncthreads();                               // B3: Seg ready

    // ---- P4: scan phase c, both tiles; Q overwrites E in place ----
    {
        float offr0 = 0.f, offi0 = 0.f, offr1 = 0.f, offi1 = 0.f;
        #pragma unroll
        for (int gp = 0; gp < 7; ++gp) {
            const float2 s0 = *(const float2*)&Seg[0][d * 18 + (gp << 1)];
            const float2 s1 = *(const float2*)&Seg[1][d * 18 + (gp << 1)];
            const bool take = gp < g;
            float nr = fmaf(S8r, offr0, fmaf(-S8i, offi0, s0.x));
            float ni = fmaf(S8r, offi0, fmaf(S8i, offr0, s0.y));
            offr0 = take ? nr : offr0; offi0 = take ? ni : offi0;
            nr = fmaf(S8r, offr1, fmaf(-S8i, offi1, s1.x));
            ni = fmaf(S8r, offi1, fmaf(S8i, offr1, s1.y));
            offr1 = take ? nr : offr1; offi1 = take ? ni : offi1;
        }
        float Gr = vv, Gi = 0.f;                   // v * A^(8g), shared by tiles
        if (g & 1) { float nr, ni; CMUL(nr, ni, Gr, Gi, S8r, S8i);   Gr = nr; Gi = ni; }
        if (g & 2) { float nr, ni; CMUL(nr, ni, Gr, Gi, S16r, S16i); Gr = nr; Gi = ni; }
        if (g & 4) { float nr, ni; CMUL(nr, ni, Gr, Gi, S32r, S32i); Gr = nr; Gi = ni; }
        const float wrr = c1.z, wri = c1.w;
        float Gr1 = Gr, Gi1 = Gi;                  // separate G walkers per tile
        #pragma unroll
        for (int i = 0; i < 8; ++i) {
            const int c = cb + i;
            float Qr = fmaf(wrr, offr0, fmaf(-wri, offi0, Gr));
            float Qi = fmaf(wrr, offi0, fmaf(wri, offr0, Gi));
            UsA[c * STR + d]      = (short)f2bf(Qr);
            UsA[c * STR + 32 + d] = (short)f2bf(Qi);
            Qr = fmaf(wrr, offr1, fmaf(-wri, offi1, Gr1));
            Qi = fmaf(wrr, offi1, fmaf(wri, offr1, Gi1));
            UsB[c * STR + d]      = (short)f2bf(Qr);
            UsB[c * STR + 32 + d] = (short)f2bf(Qi);
            float nr = fmaf(Ar, offr0, fmaf(-Ai, offi0, Er[0][i]));
            float ni = fmaf(Ar, offi0, fmaf(Ai, offr0, Ei[0][i]));
            offr0 = nr; offi0 = ni;
            nr = fmaf(Ar, offr1, fmaf(-Ai, offi1, Er[1][i]));
            ni = fmaf(Ar, offi1, fmaf(Ai, offr1, Ei[1][i]));
            offr1 = nr; offi1 = ni;
            float nGr, nGi;
            CMUL(nGr, nGi, Ar, Ai, Gr, Gi);
            Gr = nGr; Gi = nGi;
            CMUL(nGr, nGi, Ar, Ai, Gr1, Gi1);
            Gr1 = nGr; Gi1 = nGi;
        }
    }
    __syncthreads();                               // B4: Q ready

    // ---- P5: mm3 both tiles + stores (no u re-read; D folded into H) ----
    #pragma unroll
    for (int kh = 0; kh < 2; ++kh) {
        const int k0 = kh << 5;
        #pragma unroll
        for (int nt = 0; nt < 4; ++nt) {
            const int boff = ((nt << 4) + rowi) * STR + k0 + (quad << 3);
            const short8 bQ0 = *(const short8*)&UsA[boff];
            const short8 bQ1 = *(const short8*)&UsB[boff];
            accY0[nt] = __builtin_amdgcn_mfma_f32_16x16x32_bf16(aR[kh], bQ0, accY0[nt], 0, 0, 0);
            accY1[nt] = __builtin_amdgcn_mfma_f32_16x16x32_bf16(aR[kh], bQ1, accY1[nt], 0, 0, 0);
        }
    }
    float* op0 = out + ((((size_t)(bp * 2) * HH) + hh) << 12);
    float* op1 = out + ((((size_t)(bp * 2 + 1) * HH) + hh) << 12);
    #pragma unroll
    for (int nt = 0; nt < 4; ++nt) {
        const int c    = (nt << 4) + rowi;
        const int toff = m0 + (quad << 2);
        *(float4*)&op0[c * 64 + toff] =
            make_float4(accY0[nt][0], accY0[nt][1], accY0[nt][2], accY0[nt][3]);
        *(float4*)&op1[c * 64 + toff] =
            make_float4(accY1[nt][0], accY1[nt][1], accY1[nt][2], accY1[nt][3]);
    }
}

extern "C" void kernel_launch(void* const* d_in, const int* in_sizes, int n_in,
                              void* d_out, int out_size, void* d_ws, size_t ws_size,
                              hipStream_t stream) {
    const float* u     = (const float*)d_in[0];
    const float* theta = (const float*)d_in[1];
    const float* a     = (const float*)d_in[2];
    const float* Dp    = (const float*)d_in[3];
    const float* b_p   = (const float*)d_in[4];
    const float* c_p   = (const float*)d_in[5];
    const float* x0    = (const float*)d_in[6];
    float* out = (float*)d_out;
    char* ws = (char*)d_ws;
    unsigned short* Hm = (unsigned short*)(ws + WS_H);
    unsigned short* Pm = (unsigned short*)(ws + WS_P);
    unsigned short* Rm = (unsigned short*)(ws + WS_R);
    float4*         C1 = (float4*)(ws + WS_C1);
    float*          C2 = (float*)(ws + WS_C2);

    hipLaunchKernelGGL(s4_pre_kernel, dim3(HH), dim3(256), 0, stream,
                       theta, a, b_p, c_p, x0, Dp, Hm, Pm, Rm, C1, C2);
    hipLaunchKernelGGL(s4_main_kernel, dim3(HH * 4), dim3(256), 0, stream,
                       u, Hm, Pm, Rm, C1, C2, out);
}